// Round 1
// baseline (257.654 us; speedup 1.0000x reference)
//
#include <hip/hip_runtime.h>
#include <hip/hip_bf16.h>

#define WINDOW 5
#define DIM 1024
#define FEAT 1024
#define SEQ 128
#define BATCH 128
#define MTOT (BATCH*SEQ)      // 16384
#define NTOT (WINDOW*FEAT)    // 5120
#define KTOT DIM

#define BM 128
#define BN 128
#define BK 32

typedef short short8 __attribute__((ext_vector_type(8)));
typedef float f32x4 __attribute__((ext_vector_type(4)));

static __device__ __forceinline__ float bf2f(unsigned short u) {
  union { unsigned int i; float f; } c; c.i = ((unsigned int)u) << 16; return c.f;
}
static __device__ __forceinline__ unsigned short f2bf(float f) {
  union { float f; unsigned int i; } c; c.f = f;
  unsigned int i = c.i;
  unsigned int lsb = (i >> 16) & 1u;
  i += 0x7fffu + lsb;            // round-to-nearest-even
  return (unsigned short)(i >> 16);
}

// ---------------- x fp32 -> bf16 ----------------
__global__ __launch_bounds__(256) void convert_x(const float* __restrict__ x,
                                                 unsigned short* __restrict__ xb) {
  int i = blockIdx.x * 256 + threadIdx.x;       // one float4 per thread
  float4 v = ((const float4*)x)[i];
  ushort4 o;
  o.x = f2bf(v.x); o.y = f2bf(v.y); o.z = f2bf(v.z); o.w = f2bf(v.w);
  ((ushort4*)xb)[i] = o;
}

// ---------------- Ws[w][d][f] fp32 -> WsT[w][f][d] bf16 ----------------
__global__ __launch_bounds__(256) void transpose_ws(const float* __restrict__ Ws,
                                                    unsigned short* __restrict__ WsT) {
  __shared__ float tile[32][33];
  int w  = blockIdx.z;
  int f0 = blockIdx.x * 32, d0 = blockIdx.y * 32;
  int tx = threadIdx.x, ty = threadIdx.y;       // (32,8)
  const float* src = Ws + ((size_t)w * DIM + d0) * FEAT + f0;
  #pragma unroll
  for (int i = 0; i < 4; i++)
    tile[ty + 8*i][tx] = src[(size_t)(ty + 8*i) * FEAT + tx];
  __syncthreads();
  unsigned short* dst = WsT + ((size_t)w * FEAT + f0) * DIM + d0;
  #pragma unroll
  for (int i = 0; i < 4; i++)
    dst[(size_t)(ty + 8*i) * DIM + tx] = f2bf(tile[tx][ty + 8*i]);
}

// ---------------- GEMM: proj[m][n] = xb[m][k] * WsT-as-B[k][n], bf16 out ----------------
__global__ __launch_bounds__(256) void gemm_kernel(
    const unsigned short* __restrict__ xb,   // [MTOT][KTOT] bf16
    const unsigned short* __restrict__ wst,  // [W][FEAT][DIM] bf16 (K-contiguous)
    unsigned short* __restrict__ proj,       // [chunk_rows][NTOT] bf16, chunk-local
    int m_base)
{
  __shared__ unsigned short As[BM * BK];   // [128][32] linear (global_load_lds dest)
  __shared__ unsigned short Bs[BN * BK];   // [128][32] linear

  const int tid  = threadIdx.x;
  const int wid  = tid >> 6;
  const int lane = tid & 63;

  const int mt = blockIdx.x;
  const int n0 = blockIdx.y * BN;
  const int w  = n0 >> 10;            // which Ws
  const int f0 = n0 & 1023;

  const unsigned short* aG = xb  + (size_t)(m_base + mt * BM) * KTOT;
  const unsigned short* bG = wst + ((size_t)w * FEAT + f0) * DIM;

  // staging geometry: segment s covers rows 16s..16s+15; lane l -> row 16s + l/4, elem (l%4)*8
  const int r_in_seg = lane >> 2;
  const int c8       = (lane & 3) << 3;

  f32x4 acc[4][4];
  #pragma unroll
  for (int i = 0; i < 4; i++)
    #pragma unroll
    for (int j = 0; j < 4; j++)
      acc[i][j] = (f32x4){0.f, 0.f, 0.f, 0.f};

  const int wm = wid >> 1, wn = wid & 1;   // 2x2 waves, 64x64 each
  const int fr_row = lane & 15;
  const int fr_k   = (lane >> 4) << 3;     // 0,8,16,24

  for (int kt = 0; kt < KTOT / BK; kt++) {
    const int k0 = kt * BK;
    // wave wid stages segments {wid, wid+4} of A and B (1KB each, lane l -> +16B*l)
    {
      int s0 = wid, s1 = wid + 4;
      __builtin_amdgcn_global_load_lds(
          (const __attribute__((address_space(1))) void*)(aG + (size_t)(s0*16 + r_in_seg)*KTOT + k0 + c8),
          (__attribute__((address_space(3))) void*)(As + s0*512), 16, 0, 0);
      __builtin_amdgcn_global_load_lds(
          (const __attribute__((address_space(1))) void*)(aG + (size_t)(s1*16 + r_in_seg)*KTOT + k0 + c8),
          (__attribute__((address_space(3))) void*)(As + s1*512), 16, 0, 0);
      __builtin_amdgcn_global_load_lds(
          (const __attribute__((address_space(1))) void*)(bG + (size_t)(s0*16 + r_in_seg)*DIM + k0 + c8),
          (__attribute__((address_space(3))) void*)(Bs + s0*512), 16, 0, 0);
      __builtin_amdgcn_global_load_lds(
          (const __attribute__((address_space(1))) void*)(bG + (size_t)(s1*16 + r_in_seg)*DIM + k0 + c8),
          (__attribute__((address_space(3))) void*)(Bs + s1*512), 16, 0, 0);
    }
    __syncthreads();   // drains vmcnt then barrier

    short8 a[4], b[4];
    #pragma unroll
    for (int i = 0; i < 4; i++)
      a[i] = *(const short8*)(As + (wm*64 + i*16 + fr_row) * BK + fr_k);
    #pragma unroll
    for (int j = 0; j < 4; j++)
      b[j] = *(const short8*)(Bs + (wn*64 + j*16 + fr_row) * BK + fr_k);

    #pragma unroll
    for (int i = 0; i < 4; i++)
      #pragma unroll
      for (int j = 0; j < 4; j++)
        acc[i][j] = __builtin_amdgcn_mfma_f32_16x16x32_bf16(a[i], b[j], acc[i][j], 0, 0, 0);

    __syncthreads();   // all reads done before next stage overwrites
  }

  // epilogue: C/D layout col=lane&15, row=(lane>>4)*4+reg
  const int crow = (lane >> 4) << 2;
  const int ccol = lane & 15;
  unsigned short* outp = proj + (size_t)(mt * BM) * NTOT + n0;
  #pragma unroll
  for (int i = 0; i < 4; i++)
    #pragma unroll
    for (int j = 0; j < 4; j++)
      #pragma unroll
      for (int r = 0; r < 4; r++) {
        int mrow = wm*64 + i*16 + crow + r;
        int ncol = wn*64 + j*16 + ccol;
        outp[(size_t)mrow * NTOT + ncol] = f2bf(acc[i][j][r]);
      }
}

// ---------------- max-plus scan over l + tanh ----------------
__global__ __launch_bounds__(256) void scan_kernel(
    const unsigned short* __restrict__ proj,  // [nbatch*SEQ][NTOT] bf16, chunk-local
    const float* __restrict__ bias,
    float* __restrict__ out, int b_base, int nbatch)
{
  int tid = blockIdx.x * 256 + threadIdx.x;
  int bb  = tid >> 9;                 // local batch (512 threads per batch)
  if (bb >= nbatch) return;
  int f0  = (tid & 511) << 1;         // 2 f's per thread

  const unsigned short* p = proj + (size_t)bb * SEQ * NTOT + f0;

  float h[5][2];
  #pragma unroll
  for (int k = 0; k < 5; k++) { h[k][0] = 0.f; h[k][1] = 0.f; }

  for (int l = 0; l < SEQ; l++) {
    float pw[5][2];
    #pragma unroll
    for (int w = 0; w < 5; w++) {
      unsigned int v = *(const unsigned int*)(p + (size_t)l * NTOT + (w << 10));
      pw[w][0] = bf2f((unsigned short)(v & 0xffffu));
      pw[w][1] = bf2f((unsigned short)(v >> 16));
    }
    #pragma unroll
    for (int c = 0; c < 2; c++) {
      h[4][c] = fmaxf(h[3][c] + pw[4][c], h[4][c]);
      h[3][c] = fmaxf(h[2][c] + pw[3][c], h[3][c]);
      h[2][c] = fmaxf(h[1][c] + pw[2][c], h[2][c]);
      h[1][c] = fmaxf(h[0][c] + pw[1][c], h[1][c]);
      h[0][c] = fmaxf(pw[0][c],          h[0][c]);
    }
  }
  float b0 = bias[f0], b1 = bias[f0 + 1];
  size_t ob = (size_t)(b_base + bb) * FEAT + f0;
  out[ob]     = tanhf(h[4][0] + b0);
  out[ob + 1] = tanhf(h[4][1] + b1);
}

extern "C" void kernel_launch(void* const* d_in, const int* in_sizes, int n_in,
                              void* d_out, int out_size, void* d_ws, size_t ws_size,
                              hipStream_t stream) {
  const float* x  = (const float*)d_in[0];
  const float* Ws = (const float*)d_in[1];
  const float* b  = (const float*)d_in[2];
  float* out = (float*)d_out;

  char* ws = (char*)d_ws;
  const size_t XB_BYTES  = (size_t)MTOT * KTOT * 2;           // 33,554,432
  const size_t WST_BYTES = (size_t)WINDOW * FEAT * DIM * 2;   // 10,485,760
  unsigned short* xb   = (unsigned short*)ws;
  unsigned short* wst  = (unsigned short*)(ws + XB_BYTES);
  char* projbase = ws + XB_BYTES + WST_BYTES;

  const size_t per_batch = (size_t)SEQ * NTOT * 2;            // 1,310,720
  size_t avail = (ws_size > XB_BYTES + WST_BYTES) ? (ws_size - XB_BYTES - WST_BYTES) : per_batch;
  int nb = (int)(avail / per_batch);
  if (nb > BATCH) nb = BATCH;
  if (nb < 1) nb = 1;

  hipLaunchKernelGGL(convert_x, dim3(MTOT * KTOT / 4 / 256), dim3(256), 0, stream, x, xb);
  hipLaunchKernelGGL(transpose_ws, dim3(FEAT / 32, DIM / 32, WINDOW), dim3(32, 8), 0, stream, Ws, wst);

  for (int done = 0; done < BATCH; done += nb) {
    int cur = (BATCH - done < nb) ? (BATCH - done) : nb;
    unsigned short* proj = (unsigned short*)projbase;
    hipLaunchKernelGGL(gemm_kernel, dim3(cur, NTOT / BN), dim3(256), 0, stream,
                       xb, wst, proj, done * SEQ);
    hipLaunchKernelGGL(scan_kernel, dim3(cur * 2), dim3(256), 0, stream,
                       proj, b, out, done, cur);
  }
}